// Round 8
// baseline (152.184 us; speedup 1.0000x reference)
//
#include <hip/hip_runtime.h>
#include <hip/hip_bf16.h>

// out[b,o,n] = sum_{k,c} input[b,c,n] * weight[o,k,c] * score[b,k,n]
// B=8, C_IN=16, C_OUT=16, K=4, N=524288. fp32 in/out.
//
// MFMA formulation: out[b,:,n] = W'(16x64) . Z(64,n),  Z[k*16+c, n] = a[k,n]*x[c,n].
// One wave-tile = 16(o) x 16(n) via 2x mfma_f32_16x16x32_bf16 (layout verified r6).
//
// Rounds 5-7 lesson: VGPR-resident load clustering loses to the regalloc
// heuristic (compiler picked 24..44 VGPR, serializing loads -> latency-bound).
// Fix: register-free MLP via global_load_lds into a double-buffered LDS slab.
// Outstanding bytes/CU ~ 4 blocks x 20 KB = 80 KB >> 23 KB needed to saturate
// 6.3 TB/s at ~900cy latency. 2-phase pipeline, one barrier per stage.

constexpr int B     = 8;
constexpr int C_IN  = 16;
constexpr int C_OUT = 16;
constexpr int KK    = 4;
constexpr long NN   = 524288;               // 2^19
constexpr int W     = 256;                  // floats per row per stage (1 KB)
constexpr int ROWS  = C_IN + KK;            // 20 staged rows (16 x + 4 score)
constexpr int STAGES_PER_BLOCK = 16;
constexpr int BLOCKS_PER_BATCH = (int)(NN / (W * STAGES_PER_BLOCK));  // 128
constexpr int GRID  = B * BLOCKS_PER_BATCH; // 1024 -> 4 blocks/CU (LDS-exact)

typedef short bf16x8 __attribute__((ext_vector_type(8)));
typedef float f32x4  __attribute__((ext_vector_type(4)));

__device__ inline short f2bf(float f) {
    return __builtin_bit_cast(short, __float2bfloat16(f));
}

// Direct global->LDS async copy, 16 B/lane. LDS dest is wave-uniform base +
// lane*16; global src is per-lane. Zero VGPRs for results; tracked by vmcnt.
__device__ inline void gll16(const float* gsrc, float* ldst) {
    __builtin_amdgcn_global_load_lds(
        (const __attribute__((address_space(1))) unsigned int*)gsrc,
        (__attribute__((address_space(3))) unsigned int*)ldst,
        16, 0, 0);
}

__global__ __launch_bounds__(256) void
TransformConv1d_39264591020709_kernel(const float* __restrict__ in,
                                      const float* __restrict__ w,
                                      const float* __restrict__ sc,
                                      float* __restrict__ out) {
    __shared__ float lds[2][ROWS][W];       // 2 x 20 KB

    const int tid  = threadIdx.x;
    const int lane = tid & 63;
    const int wid  = tid >> 6;              // wave 0..3
    const int g    = lane >> 4;             // lane group 0..3
    const int col  = lane & 15;

    const int  bi = blockIdx.x;
    const int  b  = bi >> 7;                               // /BLOCKS_PER_BATCH
    const long n0 = (long)(bi & (BLOCKS_PER_BATCH - 1)) * (W * STAGES_PER_BLOCK);

    const int ktap = g >> 1;                // score tap (and ktap+2 for K-half 1)
    const int c0   = (g & 1) * 8;           // input-channel half

    // A operand (weights): lane holds W'[o=col][kc=g*8+i (+32)] (layout verified r6).
    bf16x8 w0, w1;
#pragma unroll
    for (int i = 0; i < 8; ++i) {
        w0[i] = f2bf(w[(col * KK + ktap    ) * C_IN + c0 + i]);
        w1[i] = f2bf(w[(col * KK + ktap + 2) * C_IN + c0 + i]);
    }

    // ---- stage: 5 rows per wave, 1 KB per row, register-free ----
    auto STAGE = [&](int s, int buf) {
        const long noff = n0 + (long)s * W;
#pragma unroll
        for (int j = 0; j < 5; ++j) {
            const int r = wid * 5 + j;      // rows 0..19 across 4 waves
            const float* src = (r < C_IN)
                ? in + ((long)(b * C_IN + r)) * NN + noff + lane * 4
                : sc + ((long)(b * KK + (r - C_IN))) * NN + noff + lane * 4;
            gll16(src, &lds[buf][r][0]);
        }
    };

    // ---- compute: 4 tiles per wave out of LDS ----
    auto COMPUTE = [&](int s, int buf) {
        const long noff = n0 + (long)s * W;
#pragma unroll
        for (int u = 0; u < 4; ++u) {
            const int nt = (wid * 4 + u) * 16;
            float xv[8];
#pragma unroll
            for (int i = 0; i < 8; ++i) xv[i] = lds[buf][c0 + i][nt + col];
            const float a0 = lds[buf][C_IN + ktap    ][nt + col];
            const float a1 = lds[buf][C_IN + ktap + 2][nt + col];

            bf16x8 z0, z1;
#pragma unroll
            for (int i = 0; i < 8; ++i) {
                z0[i] = f2bf(a0 * xv[i]);
                z1[i] = f2bf(a1 * xv[i]);
            }
            f32x4 acc = {0.f, 0.f, 0.f, 0.f};
            acc = __builtin_amdgcn_mfma_f32_16x16x32_bf16(w0, z0, acc, 0, 0, 0);
            acc = __builtin_amdgcn_mfma_f32_16x16x32_bf16(w1, z1, acc, 0, 0, 0);

            // D[row=g*4+r][col]; row = o. Write-once stream -> non-temporal.
#pragma unroll
            for (int r = 0; r < 4; ++r)
                __builtin_nontemporal_store(acc[r],
                    out + ((long)(b * C_OUT + g * 4 + r)) * NN + noff + nt + col);
        }
    };

    // ---- 2-phase pipeline: issue next stage before computing current ----
    int cur = 0;
    STAGE(0, 0);
    for (int s = 0; s < STAGES_PER_BLOCK; ++s) {
        __syncthreads();                    // drains own vmcnt; all waves' staging done
        if (s + 1 < STAGES_PER_BLOCK) STAGE(s + 1, cur ^ 1);
        COMPUTE(s, cur);
        cur ^= 1;
    }
}

extern "C" void kernel_launch(void* const* d_in, const int* in_sizes, int n_in,
                              void* d_out, int out_size, void* d_ws, size_t ws_size,
                              hipStream_t stream) {
    const float* in = (const float*)d_in[0];   // (B, C_IN, N)
    const float* w  = (const float*)d_in[1];   // (C_OUT, K, C_IN)
    const float* sc = (const float*)d_in[2];   // (B, K, N)
    float* out = (float*)d_out;                // (B, C_OUT, N)

    TransformConv1d_39264591020709_kernel<<<GRID, 256, 0, stream>>>(in, w, sc, out);
}

// Round 9
// 116.093 us; speedup vs baseline: 1.3109x; 1.3109x over previous
//
#include <hip/hip_runtime.h>
#include <hip/hip_bf16.h>

// out[b,o,n] = sum_{k,c} input[b,c,n] * weight[o,k,c] * score[b,k,n]
// B=8, C_IN=16, C_OUT=16, K=4, N=524288. fp32 in/out.
// MFMA: out[b,:,n] = W'(16x64) . Z(64,n), Z[k*16+c,n] = a[k,n]*x[c,n].
//
// r8 lessons: (a) __syncthreads drains prefetch glls + 256 scalar-nt store
// acks each stage; (b) scalar nt stores amplified writes 256->333MB.
// r9: stage x only (32KB LDS); scores direct to VGPR; output transposed
// through the consumed x-buffer (wave-quarter-local, barrier-free) into
// 256B-segment nt dwordx4 stores; raw s_barrier + counted vmcnt(4) so the
// prefetch is never drained in the main loop.

constexpr int B     = 8;
constexpr int C_IN  = 16;
constexpr int C_OUT = 16;
constexpr int KK    = 4;
constexpr long NN   = 524288;            // 2^19
constexpr int W     = 256;               // floats per staged row (1 KB)
constexpr int S     = 8;                 // stages per block
constexpr int BPB   = (int)(NN / (W * S));  // 256 blocks per batch
constexpr int GRID  = B * BPB;           // 2048

typedef short bf16x8 __attribute__((ext_vector_type(8)));
typedef float f32x4  __attribute__((ext_vector_type(4)));

__device__ inline short f2bf(float f) {
    return __builtin_bit_cast(short, __float2bfloat16(f));
}

// global->LDS direct copy, 16 B/lane, zero result VGPRs (tracked by vmcnt).
__device__ inline void gll16(const float* gsrc, float* ldst) {
    __builtin_amdgcn_global_load_lds(
        (const __attribute__((address_space(1))) unsigned int*)gsrc,
        (__attribute__((address_space(3))) unsigned int*)ldst,
        16, 0, 0);
}

__global__ __launch_bounds__(256, 4) void
TransformConv1d_39264591020709_kernel(const float* __restrict__ in,
                                      const float* __restrict__ w,
                                      const float* __restrict__ sc,
                                      float* __restrict__ out) {
    __shared__ float lds[2][C_IN][W];    // 32 KB, double-buffered x slab

    const int tid  = threadIdx.x;
    const int lane = tid & 63;
    const int wid  = tid >> 6;           // wave 0..3 (owns cols wid*64..+63)
    const int g    = lane >> 4;          // lane group 0..3
    const int col  = lane & 15;

    const int  bi = blockIdx.x;
    const int  b  = bi >> 8;             // / BPB (=256)
    const long n0 = (long)(bi & (BPB - 1)) * (W * S);

    const int ktap = g >> 1;             // score taps {ktap, ktap+2}
    const int c0   = (g & 1) * 8;        // input-channel half

    // A operand (weights): lane holds W'[o=col][kc=g*8+i (+32)] (verified r6-r8).
    bf16x8 w0, w1;
#pragma unroll
    for (int i = 0; i < 8; ++i) {
        w0[i] = f2bf(w[(col * KK + ktap    ) * C_IN + c0 + i]);
        w1[i] = f2bf(w[(col * KK + ktap + 2) * C_IN + c0 + i]);
    }

    const float* inb  = in  + (long)b * C_IN  * NN;
    const float* scb  = sc  + (long)b * KK    * NN;
    float*       outb = out + (long)b * C_OUT * NN;

    // stage: 4 rows per wave, 1 KB (=1 gll instr) per row.
    auto STAGE = [&](int s) {
        const long noff = n0 + (long)s * W;
#pragma unroll
        for (int j = 0; j < 4; ++j) {
            const int r = wid * 4 + j;
            gll16(inb + (long)r * NN + noff + lane * 4, &lds[s & 1][r][0]);
        }
    };

    STAGE(0);
    __syncthreads();                     // prologue drain (vmcnt(0)+barrier) — ok once

    for (int s = 0; s < S; ++s) {
        const long nb = n0 + (long)s * W;
        float (*X)[W] = lds[s & 1];

        // ---- scores -> VGPR (issued before glls so counted waits don't drain them)
        float a0[4], a1[4];
#pragma unroll
        for (int u = 0; u < 4; ++u) {
            const int nc = (wid * 4 + u) * 16 + col;
            a0[u] = scb[(long)ktap       * NN + nb + nc];
            a1[u] = scb[(long)(ktap + 2) * NN + nb + nc];
        }
        __builtin_amdgcn_sched_barrier(0);

        // ---- prefetch next slab (4 glls, in flight across the whole stage)
        if (s + 1 < S) STAGE(s + 1);
        __builtin_amdgcn_sched_barrier(0);

        // ---- compute 4 tiles; write output into the consumed x-slab
        // (wave touches ONLY its own 64-col quarter for x-reads and out-writes)
#pragma unroll
        for (int u = 0; u < 4; ++u) {
            const int nt = (wid * 4 + u) * 16;
            float xv[8];
#pragma unroll
            for (int i = 0; i < 8; ++i) xv[i] = X[c0 + i][nt + col];
            bf16x8 z0, z1;
#pragma unroll
            for (int i = 0; i < 8; ++i) {
                z0[i] = f2bf(a0[u] * xv[i]);
                z1[i] = f2bf(a1[u] * xv[i]);
            }
            f32x4 acc = {0.f, 0.f, 0.f, 0.f};
            acc = __builtin_amdgcn_mfma_f32_16x16x32_bf16(w0, z0, acc, 0, 0, 0);
            acc = __builtin_amdgcn_mfma_f32_16x16x32_bf16(w1, z1, acc, 0, 0, 0);
#pragma unroll
            for (int r = 0; r < 4; ++r)
                X[g * 4 + r][nt + col] = acc[r];   // D[row=g*4+r][col] -> LDS
        }
        __builtin_amdgcn_sched_barrier(0);

        // ---- read back own quarter as b128, store 256B-segment nt dwordx4
#pragma unroll
        for (int q = 0; q < 4; ++q) {
            const int row = q * 4 + (lane >> 4);
            const int cq  = wid * 64 + (lane & 15) * 4;
            f32x4 v = *(const f32x4*)&X[row][cq];          // ds_read_b128
            __builtin_nontemporal_store(v,
                (f32x4*)(outb + (long)row * NN + nb + cq));
        }

        // ---- counted wait: everything except the 4 newest (this stage's stores)
        // retired => next slab's glls complete; stores stay in flight.
        if (s + 1 < S) {
            asm volatile("s_waitcnt vmcnt(4)" ::: "memory");
            __builtin_amdgcn_sched_barrier(0);
            __builtin_amdgcn_s_barrier();
            __builtin_amdgcn_sched_barrier(0);
        }
    }
}

extern "C" void kernel_launch(void* const* d_in, const int* in_sizes, int n_in,
                              void* d_out, int out_size, void* d_ws, size_t ws_size,
                              hipStream_t stream) {
    const float* in = (const float*)d_in[0];   // (B, C_IN, N)
    const float* w  = (const float*)d_in[1];   // (C_OUT, K, C_IN)
    const float* sc = (const float*)d_in[2];   // (B, K, N)
    float* out = (float*)d_out;                // (B, C_OUT, N)

    TransformConv1d_39264591020709_kernel<<<GRID, 256, 0, stream>>>(in, w, sc, out);
}